// Round 1
// baseline (363.145 us; speedup 1.0000x reference)
//
#include <hip/hip_runtime.h>
#include <hip/hip_bf16.h>

typedef __attribute__((ext_vector_type(8))) short bf16x8;
typedef __attribute__((ext_vector_type(4))) float f32x4;
typedef unsigned short ushort_t;

#define NB 4
#define NH 128
#define NW 128
#define NC 128
#define NF 256
#define NKC 1152   // 9*128
#define NPIX 65536 // NB*NH*NW

// ws layout (bytes), all 16B-aligned:
//   0        : W_t   bf16 [256][1152]  (294912 elems, 589824 B)
//   589824   : Wom_t bf16 [32][1152]   (36864 elems,  73728 B)
//   663552   : offs  f32  [65536][18]  (4718592 B)
//   5382144  : modsig f32 [65536][9]   (2359296 B)
// total ~7.74 MB

__device__ __forceinline__ ushort_t f2bf(float f) {
    union { float f; unsigned int u; } v; v.f = f;
    unsigned int u = v.u;
    unsigned int r = (u + 0x7fffu + ((u >> 16) & 1u)) >> 16;
    return (ushort_t)r;
}

// ---------------- K0: weight transpose + bf16 convert ----------------
__global__ __launch_bounds__(256) void k0_prep(
    const float* __restrict__ kern, const float* __restrict__ offw,
    const float* __restrict__ modw, ushort_t* __restrict__ wt,
    ushort_t* __restrict__ wom) {
    int tid = blockIdx.x * 256 + threadIdx.x;
    if (tid < 294912) {
        int f = tid / 1152, e = tid % 1152;
        wt[tid] = f2bf(kern[e * 256 + f]);
    } else if (tid < 294912 + 36864) {
        int t2 = tid - 294912;
        int o = t2 / 1152, e = t2 % 1152;
        float v = 0.f;
        if (o < 18) v = offw[e * 18 + o];
        else if (o < 27) v = modw[e * 9 + (o - 18)];
        wom[t2] = f2bf(v);
    }
}

// ---------------- K1: offset/mod conv (implicit GEMM, bf16 MFMA) -----
// One block per (b,h) row: M=128 pixels, N=32 (27 used), K=1152.
__global__ __launch_bounds__(256) void k1_offsets(
    const float* __restrict__ x, const ushort_t* __restrict__ wom,
    const float* __restrict__ offb, const float* __restrict__ modb,
    float* __restrict__ offs, float* __restrict__ modsig) {
    __shared__ ushort_t As[128 * 136];
    const int bid = blockIdx.x;
    const int b = bid >> 7, h = bid & 127;
    const int t = threadIdx.x;
    const int lane = t & 63, wv = t >> 6;      // 4 waves
    const int ln = lane & 15, quad = lane >> 4;

    f32x4 acc[2][2];
#pragma unroll
    for (int i = 0; i < 2; ++i)
#pragma unroll
        for (int j = 0; j < 2; ++j) acc[i][j] = (f32x4){0.f, 0.f, 0.f, 0.f};

    const int si = t >> 1;            // pixel 0..127
    const int sc = (t & 1) * 64;      // channel base

    for (int tap = 0; tap < 9; ++tap) {
        const int ky = tap / 3 - 1, kx = tap % 3 - 1;
        // stage A tile: x[b, h+ky, w+kx, :] with SAME zero padding
        const int y = h + ky;
        const int xw = si + kx;
        const bool valid = ((unsigned)y < 128u) && ((unsigned)xw < 128u);
        const float* src = x + (((b * 128 + y) * 128 + xw) * 128);
#pragma unroll
        for (int q = 0; q < 16; ++q) {
            const int c = sc + q * 4;
            float4 v = valid ? *(const float4*)(src + c) : make_float4(0.f, 0.f, 0.f, 0.f);
            ushort4 u;
            u.x = f2bf(v.x); u.y = f2bf(v.y); u.z = f2bf(v.z); u.w = f2bf(v.w);
            *(ushort4*)&As[si * 136 + c] = u;
        }
        __syncthreads();
#pragma unroll
        for (int kc = 0; kc < 4; ++kc) {
            const int col = kc * 32 + quad * 8;
            bf16x8 a0 = *(const bf16x8*)&As[(wv * 32 + ln) * 136 + col];
            bf16x8 a1 = *(const bf16x8*)&As[(wv * 32 + 16 + ln) * 136 + col];
            const ushort_t* bp = wom + tap * 128 + col;
            bf16x8 b0 = *(const bf16x8*)(bp + ln * 1152);
            bf16x8 b1 = *(const bf16x8*)(bp + (16 + ln) * 1152);
            acc[0][0] = __builtin_amdgcn_mfma_f32_16x16x32_bf16(a0, b0, acc[0][0], 0, 0, 0);
            acc[0][1] = __builtin_amdgcn_mfma_f32_16x16x32_bf16(a0, b1, acc[0][1], 0, 0, 0);
            acc[1][0] = __builtin_amdgcn_mfma_f32_16x16x32_bf16(a1, b0, acc[1][0], 0, 0, 0);
            acc[1][1] = __builtin_amdgcn_mfma_f32_16x16x32_bf16(a1, b1, acc[1][1], 0, 0, 0);
        }
        __syncthreads();
    }
    // epilogue: C/D layout col=lane&15, row=quad*4+r
#pragma unroll
    for (int mi = 0; mi < 2; ++mi) {
#pragma unroll
        for (int nt = 0; nt < 2; ++nt) {
#pragma unroll
            for (int r = 0; r < 4; ++r) {
                const int m = wv * 32 + mi * 16 + quad * 4 + r;
                const int n = nt * 16 + ln;
                const int p = bid * 128 + m;
                const float v = acc[mi][nt][r];
                if (n < 18) {
                    offs[p * 18 + n] = v + offb[n];
                } else if (n < 27) {
                    const int j = n - 18;
                    const float s = v + modb[j];
                    modsig[p * 9 + j] = 1.0f / (1.0f + expf(-s));
                }
            }
        }
    }
}

// ---------------- K2: fused bilinear sample + modulate + GEMM --------
// One block per (b,h) row: M=128 pixels, N=256, K=1152. 8 waves,
// each wave computes a 64x64 register tile (4 m-tiles x 4 n-tiles).
__global__ __launch_bounds__(512) void k2_main(
    const float* __restrict__ x, const ushort_t* __restrict__ wt,
    const float* __restrict__ offs, const float* __restrict__ modsig,
    const float* __restrict__ bias, float* __restrict__ out) {
    __shared__ ushort_t As[128 * 136];
    const int bid = blockIdx.x;
    const int b = bid >> 7;
    const int t = threadIdx.x;
    const int lane = t & 63, wv = t >> 6;      // 8 waves
    const int ln = lane & 15, quad = lane >> 4;
    const int mg = wv & 1, ng = wv >> 1;       // wave tile: m-tiles 4mg.., n-tiles 4ng..
    const int p0 = bid * 128;

    f32x4 acc[4][4];
#pragma unroll
    for (int i = 0; i < 4; ++i)
#pragma unroll
        for (int j = 0; j < 4; ++j) acc[i][j] = (f32x4){0.f, 0.f, 0.f, 0.f};

    const int si = t >> 2;            // pixel 0..127
    const int sc = (t & 3) * 32;      // channel base
    const float* xb = x + b * (128 * 128 * 128);

    for (int tap = 0; tap < 9; ++tap) {
        // ---- compute bilinear coords for my pixel (redundant x4, cheap) ----
        const int p = p0 + si;
        const float bky = (float)(tap / 3 - 1), bkx = (float)(tap % 3 - 1);
        float gy = bky + offs[p * 18 + 2 * tap];
        float gx = bkx + offs[p * 18 + 2 * tap + 1];
        gy = fminf(fmaxf(gy, 0.f), 127.f);
        gx = fminf(fmaxf(gx, 0.f), 127.f);
        const float y0f = floorf(gy), x0f = floorf(gx);
        const int y0 = (int)y0f, x0 = (int)x0f;
        const int y1 = min(y0 + 1, 127), x1 = min(x0 + 1, 127);
        const float wy1 = gy - y0f, wx1 = gx - x0f;
        const float wy0 = 1.f - wy1, wx0 = 1.f - wx1;
        const float m = modsig[p * 9 + tap];
        const float w00 = m * wy0 * wx0, w01 = m * wy0 * wx1;
        const float w10 = m * wy1 * wx0, w11 = m * wy1 * wx1;
        const float* r00 = xb + (y0 * 128 + x0) * 128;
        const float* r01 = xb + (y0 * 128 + x1) * 128;
        const float* r10 = xb + (y1 * 128 + x0) * 128;
        const float* r11 = xb + (y1 * 128 + x1) * 128;
#pragma unroll
        for (int q = 0; q < 8; ++q) {
            const int c = sc + q * 4;
            float4 v00 = *(const float4*)(r00 + c);
            float4 v01 = *(const float4*)(r01 + c);
            float4 v10 = *(const float4*)(r10 + c);
            float4 v11 = *(const float4*)(r11 + c);
            ushort4 u;
            u.x = f2bf(w00 * v00.x + w01 * v01.x + w10 * v10.x + w11 * v11.x);
            u.y = f2bf(w00 * v00.y + w01 * v01.y + w10 * v10.y + w11 * v11.y);
            u.z = f2bf(w00 * v00.z + w01 * v01.z + w10 * v10.z + w11 * v11.z);
            u.w = f2bf(w00 * v00.w + w01 * v01.w + w10 * v10.w + w11 * v11.w);
            *(ushort4*)&As[si * 136 + c] = u;
        }
        __syncthreads();
        // ---- MFMA over this tap's K=128 ----
#pragma unroll
        for (int kc = 0; kc < 4; ++kc) {
            const int col = kc * 32 + quad * 8;
            bf16x8 a[4], bf[4];
#pragma unroll
            for (int mi = 0; mi < 4; ++mi)
                a[mi] = *(const bf16x8*)&As[((mg * 4 + mi) * 16 + ln) * 136 + col];
            const ushort_t* bp = wt + ln * 1152 + tap * 128 + col;
#pragma unroll
            for (int nj = 0; nj < 4; ++nj)
                bf[nj] = *(const bf16x8*)(bp + ((ng * 4 + nj) * 16) * 1152);
#pragma unroll
            for (int mi = 0; mi < 4; ++mi)
#pragma unroll
                for (int nj = 0; nj < 4; ++nj)
                    acc[mi][nj] = __builtin_amdgcn_mfma_f32_16x16x32_bf16(a[mi], bf[nj], acc[mi][nj], 0, 0, 0);
        }
        __syncthreads();
    }
    // ---- epilogue: C/D layout col=lane&15, row=quad*4+r ----
#pragma unroll
    for (int mi = 0; mi < 4; ++mi) {
#pragma unroll
        for (int nj = 0; nj < 4; ++nj) {
            const int n = (ng * 4 + nj) * 16 + ln;
            const float bs = bias[n];
#pragma unroll
            for (int r = 0; r < 4; ++r) {
                const int m = (mg * 4 + mi) * 16 + quad * 4 + r;
                out[(p0 + m) * 256 + n] = acc[mi][nj][r] + bs;
            }
        }
    }
}

extern "C" void kernel_launch(void* const* d_in, const int* in_sizes, int n_in,
                              void* d_out, int out_size, void* d_ws, size_t ws_size,
                              hipStream_t stream) {
    const float* x    = (const float*)d_in[0];
    const float* offw = (const float*)d_in[1];
    const float* offb = (const float*)d_in[2];
    const float* modw = (const float*)d_in[3];
    const float* modb = (const float*)d_in[4];
    const float* kern = (const float*)d_in[5];
    const float* bias = (const float*)d_in[6];
    float* out = (float*)d_out;

    char* ws = (char*)d_ws;
    ushort_t* wt     = (ushort_t*)(ws);                  // [256][1152] bf16
    ushort_t* wom    = (ushort_t*)(ws + 589824);         // [32][1152] bf16
    float*    offs   = (float*)(ws + 663552);            // [65536][18] f32
    float*    modsig = (float*)(ws + 5382144);           // [65536][9] f32

    k0_prep<<<1296, 256, 0, stream>>>(kern, offw, modw, wt, wom);
    k1_offsets<<<512, 256, 0, stream>>>(x, wom, offb, modb, offs, modsig);
    k2_main<<<512, 512, 0, stream>>>(x, wt, offs, modsig, bias, out);
}

// Round 2
// 236.691 us; speedup vs baseline: 1.5343x; 1.5343x over previous
//
#include <hip/hip_runtime.h>
#include <hip/hip_bf16.h>
#include <math.h>

typedef __attribute__((ext_vector_type(8))) short bf16x8;
typedef __attribute__((ext_vector_type(8))) unsigned short u16x8;
typedef __attribute__((ext_vector_type(4))) float f32x4;
typedef unsigned short ushort_t;

// Problem: B=4,H=W=128,C=128,F=256,K=9. out = ((bilinear-sample(x,offs)*mod) @ kernel) + bias
// ws layout (bytes):
//   0        : xbf   bf16 [4*128*128*128]          16,777,216
//   16777216 : wt2   bf16 [36][256][32]               589,824   (kcg-major, frag-contiguous)
//   17367040 : wom2  bf16 [36][32][32]                 73,728
//   17440768 : metaw f32x4 [65536*9]                9,437,184   (premult bilinear weights)
//   26877952 : metai int2  [65536*9]                4,718,592   (base elem offset, dy|dx code)
//   total 31,596,544

__device__ __forceinline__ ushort_t f2bf(float f) {
    union { float f; unsigned int u; } v; v.f = f;
    unsigned int u = v.u;
    return (ushort_t)((u + 0x7fffu + ((u >> 16) & 1u)) >> 16);
}

__device__ __forceinline__ ushort2 pk_bf16(float a, float b) {
    __hip_bfloat162 h = __float22bfloat162_rn(make_float2(a, b));
    return *(ushort2*)&h;
}

// ---------------- K0: x -> bf16, weight repack ----------------
__global__ __launch_bounds__(256) void k0_prep(
    const float* __restrict__ x, const float* __restrict__ kern,
    const float* __restrict__ offw, const float* __restrict__ modw,
    ushort_t* __restrict__ xbf, ushort_t* __restrict__ wt2,
    ushort_t* __restrict__ wom2) {
    const int gid = blockIdx.x, t = threadIdx.x;
    if (gid < 8192) {                       // x convert: 8192*256*4 = 8.39M elems
        const int idx = gid * 256 + t;
        float4 v = ((const float4*)x)[idx];
        ushort4 u;
        u.x = f2bf(v.x); u.y = f2bf(v.y); u.z = f2bf(v.z); u.w = f2bf(v.w);
        ((ushort4*)xbf)[idx] = u;
    } else if (gid < 9344) {                // wt2: 294912 elems
        const int tid = (gid - 8192) * 256 + t;
        const int kpart = tid & 31, n = (tid >> 5) & 255, kcg = tid >> 13;
        const int k = kcg * 32 + kpart;     // k = tap*128 + c
        wt2[tid] = f2bf(kern[k * 256 + n]);
    } else {                                // wom2: 36864 elems
        const int tid = (gid - 9344) * 256 + t;
        const int kpart = tid & 31, n = (tid >> 5) & 31, kcg = tid >> 10;
        const int k = kcg * 32 + kpart;
        float v = 0.f;
        if (n < 18) v = offw[k * 18 + n];
        else if (n < 27) v = modw[k * 9 + (n - 18)];
        wom2[tid] = f2bf(v);
    }
}

// ---------------- K1: offset/mod conv + bilinear metadata ----------------
// Block per (b,h). Stage 3-row bf16 halo once per channel-half (2 passes),
// MFMA M=128,N=32,K=1152, epilogue computes metaw/metai.
#define XSS 72   // padded channel stride (shorts): 144 B, 16B-aligned, 2-way banks
__global__ __launch_bounds__(256) void k1_offsets(
    const ushort_t* __restrict__ xbf, const ushort_t* __restrict__ wom2,
    const float* __restrict__ offb, const float* __restrict__ modb,
    float4* __restrict__ metaw, int2* __restrict__ metai) {
    __shared__ ushort_t xs[3 * 130 * XSS];   // 56160 B; aliased as Cs (f32[128][32]) in epilogue
    float* Cs = (float*)xs;
    const int bid = blockIdx.x;
    const int b = bid >> 7, h = bid & 127;
    const int t = threadIdx.x;
    const int lane = t & 63, wv = t >> 6;    // 4 waves
    const int ln = lane & 15, quad = lane >> 4;

    f32x4 acc[2][2];
#pragma unroll
    for (int i = 0; i < 2; ++i)
#pragma unroll
        for (int j = 0; j < 2; ++j) acc[i][j] = (f32x4){0.f, 0.f, 0.f, 0.f};

    for (int half = 0; half < 2; ++half) {
        // stage 3 rows x 128 px x 64 ch (+zero halo cols / zero OOB rows)
        for (int u = t; u < 768; u += 256) {
            const int r = u >> 8, rem = u & 255;
            const int xw = rem >> 1, sub = rem & 1;
            const int y = h + r - 1;
            ushort_t* dst = &xs[(r * 130 + xw + 1) * XSS + sub * 32];
            if ((unsigned)y < 128u) {
                const ushort_t* src = xbf + (((b * 128 + y) * 128 + xw) * 128) + half * 64 + sub * 32;
#pragma unroll
                for (int j = 0; j < 4; ++j)
                    *(int4*)(dst + j * 8) = *(const int4*)(src + j * 8);
            } else {
                const int4 z = make_int4(0, 0, 0, 0);
#pragma unroll
                for (int j = 0; j < 4; ++j) *(int4*)(dst + j * 8) = z;
            }
        }
        if (t < 48) {   // halo columns cc=0, cc=129 (3 rows x 2 sides x 64 ch)
            const int r = t >> 4, side = (t >> 3) & 1, j = t & 7;
            *(int4*)&xs[(r * 130 + side * 129) * XSS + j * 8] = make_int4(0, 0, 0, 0);
        }
        __syncthreads();
#pragma unroll
        for (int tap = 0; tap < 9; ++tap) {
            const int ky = tap / 3, kx = tap % 3;
#pragma unroll
            for (int kc = 0; kc < 2; ++kc) {
                const int col = kc * 32 + quad * 8;
                const ushort_t* arow = &xs[(ky * 130 + kx) * XSS + col];
                bf16x8 a0 = *(const bf16x8*)(arow + (wv * 32 + ln) * XSS);
                bf16x8 a1 = *(const bf16x8*)(arow + (wv * 32 + 16 + ln) * XSS);
                const int kcg = tap * 4 + half * 2 + kc;
                const ushort_t* bp = wom2 + kcg * 1024 + quad * 8;
                bf16x8 b0 = *(const bf16x8*)(bp + ln * 32);
                bf16x8 b1 = *(const bf16x8*)(bp + (ln + 16) * 32);
                acc[0][0] = __builtin_amdgcn_mfma_f32_16x16x32_bf16(a0, b0, acc[0][0], 0, 0, 0);
                acc[0][1] = __builtin_amdgcn_mfma_f32_16x16x32_bf16(a0, b1, acc[0][1], 0, 0, 0);
                acc[1][0] = __builtin_amdgcn_mfma_f32_16x16x32_bf16(a1, b0, acc[1][0], 0, 0, 0);
                acc[1][1] = __builtin_amdgcn_mfma_f32_16x16x32_bf16(a1, b1, acc[1][1], 0, 0, 0);
            }
        }
        __syncthreads();
    }
    // conv result -> LDS (only n<27 used)
#pragma unroll
    for (int mi = 0; mi < 2; ++mi)
#pragma unroll
        for (int nt = 0; nt < 2; ++nt)
#pragma unroll
            for (int r = 0; r < 4; ++r) {
                const int m = wv * 32 + mi * 16 + quad * 4 + r;
                const int n = nt * 16 + ln;
                if (n < 27) Cs[m * 32 + n] = acc[mi][nt][r];
            }
    __syncthreads();
    // bilinear metadata
    const int px = t >> 1;
    const int p = bid * 128 + px;
    for (int tap = (t & 1); tap < 9; tap += 2) {
        const float oy = Cs[px * 32 + 2 * tap] + offb[2 * tap];
        const float ox = Cs[px * 32 + 2 * tap + 1] + offb[2 * tap + 1];
        float md = Cs[px * 32 + 18 + tap] + modb[tap];
        md = 1.f / (1.f + expf(-md));
        const float gy = fminf(fmaxf((float)(tap / 3 - 1) + oy, 0.f), 127.f);
        const float gx = fminf(fmaxf((float)(tap % 3 - 1) + ox, 0.f), 127.f);
        const float y0f = floorf(gy), x0f = floorf(gx);
        const int y0 = (int)y0f, x0 = (int)x0f;
        const int dy = (y0 < 127) ? 16384 : 0;   // (y1-y0)*128*128
        const int dx = (x0 < 127) ? 128 : 0;     // (x1-x0)*128
        const float wy1 = gy - y0f, wx1 = gx - x0f;
        const float wy0 = 1.f - wy1, wx0 = 1.f - wx1;
        metaw[p * 9 + tap] = make_float4(md * wy0 * wx0, md * wy0 * wx1,
                                         md * wy1 * wx0, md * wy1 * wx1);
        metai[p * 9 + tap] = make_int2((y0 * 128 + x0) * 128, dy + dx);
    }
}

// ---------------- K2: fused sample + modulate + GEMM ----------------
// Block per (b,h): M=128, N=256, K=1152. 16 waves, wave tile 32x64.
// Double-buffered XOR-swizzled LDS A tile, 1 barrier/tap, MFMA-first order.
__device__ __forceinline__ void stage_tile(ushort_t* __restrict__ dstbuf,
                                           const float* __restrict__ xb,
                                           int si, int cb, float4 w, int2 mi_) {
    const float* r00 = xb + mi_.x;
    const float* r01 = r00 + (mi_.y & 128);
    const float* r10 = r00 + (mi_.y & 16384);
    const float* r11 = r00 + mi_.y;
    const int sw = si & 15;
#pragma unroll
    for (int q = 0; q < 2; ++q) {
        const int chunk = cb + q * 8;
        const int c = chunk * 8;
        float4 a0 = *(const float4*)(r00 + c), a1 = *(const float4*)(r00 + c + 4);
        float4 b0 = *(const float4*)(r01 + c), b1 = *(const float4*)(r01 + c + 4);
        float4 c0 = *(const float4*)(r10 + c), c1 = *(const float4*)(r10 + c + 4);
        float4 d0 = *(const float4*)(r11 + c), d1 = *(const float4*)(r11 + c + 4);
        float s0 = w.x * a0.x + w.y * b0.x + w.z * c0.x + w.w * d0.x;
        float s1 = w.x * a0.y + w.y * b0.y + w.z * c0.y + w.w * d0.y;
        float s2 = w.x * a0.z + w.y * b0.z + w.z * c0.z + w.w * d0.z;
        float s3 = w.x * a0.w + w.y * b0.w + w.z * c0.w + w.w * d0.w;
        float s4 = w.x * a1.x + w.y * b1.x + w.z * c1.x + w.w * d1.x;
        float s5 = w.x * a1.y + w.y * b1.y + w.z * c1.y + w.w * d1.y;
        float s6 = w.x * a1.z + w.y * b1.z + w.z * c1.z + w.w * d1.z;
        float s7 = w.x * a1.w + w.y * b1.w + w.z * c1.w + w.w * d1.w;
        ushort2 p01 = pk_bf16(s0, s1), p23 = pk_bf16(s2, s3);
        ushort2 p45 = pk_bf16(s4, s5), p67 = pk_bf16(s6, s7);
        u16x8 ov;
        ov[0] = p01.x; ov[1] = p01.y; ov[2] = p23.x; ov[3] = p23.y;
        ov[4] = p45.x; ov[5] = p45.y; ov[6] = p67.x; ov[7] = p67.y;
        *(u16x8*)&dstbuf[si * 128 + ((chunk ^ sw) << 3)] = ov;
    }
}

__global__ __launch_bounds__(1024) void k2_main(
    const float* __restrict__ x, const ushort_t* __restrict__ wt2,
    const float4* __restrict__ metaw, const int2* __restrict__ metai,
    const float* __restrict__ bias, float* __restrict__ out) {
    __shared__ ushort_t As[2 * 16384];   // 64 KB, two 128x128 bf16 tiles, XOR-swizzled
    const int bid = blockIdx.x;
    const int b = bid >> 7;
    const int t = threadIdx.x;
    const int lane = t & 63, wv = t >> 6;      // 16 waves
    const int ln = lane & 15, quad = lane >> 4;
    const int mg = wv & 3, ng = wv >> 2;       // wave tile: 32 rows x 64 cols
    const int p0 = bid * 128;

    f32x4 acc[2][4];
#pragma unroll
    for (int i = 0; i < 2; ++i)
#pragma unroll
        for (int j = 0; j < 4; ++j) acc[i][j] = (f32x4){0.f, 0.f, 0.f, 0.f};

    const int si = t >> 3, cb = t & 7;         // staging: 8 threads/pixel
    const int p = p0 + si;
    const float* xb = x + b * (1 << 21);

    float4 mw0 = metaw[p * 9];
    int2 mi0 = metai[p * 9];
    stage_tile(As, xb, si, cb, mw0, mi0);
    float4 mwN = metaw[p * 9 + 1];
    int2 miN = metai[p * 9 + 1];
    __syncthreads();

    for (int tap = 0; tap < 9; ++tap) {
        const ushort_t* buf = As + (tap & 1) * 16384;
        // MFMA on current tile
#pragma unroll
        for (int kc = 0; kc < 4; ++kc) {
            bf16x8 a[2], bb[4];
#pragma unroll
            for (int mi2 = 0; mi2 < 2; ++mi2) {
                const int m = (mg * 2 + mi2) * 16 + ln;
                const int chunk = kc * 4 + quad;
                a[mi2] = *(const bf16x8*)&buf[m * 128 + ((chunk ^ (m & 15)) << 3)];
            }
            const int kcg = tap * 4 + kc;
#pragma unroll
            for (int nj = 0; nj < 4; ++nj) {
                const int n = (ng * 4 + nj) * 16 + ln;
                bb[nj] = *(const bf16x8*)&wt2[(kcg * 256 + n) * 32 + quad * 8];
            }
#pragma unroll
            for (int mi2 = 0; mi2 < 2; ++mi2)
#pragma unroll
                for (int nj = 0; nj < 4; ++nj)
                    acc[mi2][nj] = __builtin_amdgcn_mfma_f32_16x16x32_bf16(
                        a[mi2], bb[nj], acc[mi2][nj], 0, 0, 0);
        }
        // stage next tile (other buffer) while other waves still MFMA
        if (tap < 8) {
            float4 mwP; int2 miP;
            if (tap < 7) { mwP = metaw[p * 9 + tap + 2]; miP = metai[p * 9 + tap + 2]; }
            stage_tile(As + ((tap + 1) & 1) * 16384, xb, si, cb, mwN, miN);
            mwN = mwP; miN = miP;
        }
        __syncthreads();
    }
    // epilogue
#pragma unroll
    for (int mi2 = 0; mi2 < 2; ++mi2)
#pragma unroll
        for (int nj = 0; nj < 4; ++nj) {
            const int n = (ng * 4 + nj) * 16 + ln;
            const float bs = bias[n];
#pragma unroll
            for (int r = 0; r < 4; ++r) {
                const int m = (mg * 2 + mi2) * 16 + quad * 4 + r;
                out[(p0 + m) * 256 + n] = acc[mi2][nj][r] + bs;
            }
        }
}

extern "C" void kernel_launch(void* const* d_in, const int* in_sizes, int n_in,
                              void* d_out, int out_size, void* d_ws, size_t ws_size,
                              hipStream_t stream) {
    const float* x    = (const float*)d_in[0];
    const float* offw = (const float*)d_in[1];
    const float* offb = (const float*)d_in[2];
    const float* modw = (const float*)d_in[3];
    const float* modb = (const float*)d_in[4];
    const float* kern = (const float*)d_in[5];
    const float* bias = (const float*)d_in[6];
    float* out = (float*)d_out;

    char* ws = (char*)d_ws;
    ushort_t* xbf   = (ushort_t*)(ws);
    ushort_t* wt2   = (ushort_t*)(ws + 16777216);
    ushort_t* wom2  = (ushort_t*)(ws + 17367040);
    float4*   metaw = (float4*)(ws + 17440768);
    int2*     metai = (int2*)(ws + 26877952);

    k0_prep<<<9488, 256, 0, stream>>>(x, kern, offw, modw, xbf, wt2, wom2);
    k1_offsets<<<512, 256, 0, stream>>>(xbf, wom2, offb, modb, metaw, metai);
    k2_main<<<512, 1024, 0, stream>>>(x, wt2, metaw, metai, bias, out);
}

// Round 3
// 184.890 us; speedup vs baseline: 1.9641x; 1.2802x over previous
//
#include <hip/hip_runtime.h>
#include <hip/hip_bf16.h>
#include <math.h>

typedef __attribute__((ext_vector_type(8))) short bf16x8;
typedef __attribute__((ext_vector_type(8))) unsigned short u16x8;
typedef __attribute__((ext_vector_type(4))) float f32x4;
typedef unsigned short ushort_t;

// Problem: B=4,H=W=128,C=128,F=256,K=9. out = ((bilinear-sample(x,offs)*mod) @ kernel) + bias
// ws layout (bytes):
//   0        : xbf   bf16 [4*128*128*128]          16,777,216
//   16777216 : wt2   bf16 [36][256][32]               589,824   (kcg-major, frag-contiguous)
//   17367040 : wom2  bf16 [36][32][32]                 73,728
//   17440768 : metaw f32x4 [65536*9]                9,437,184   (premult bilinear weights)
//   26877952 : metai int2  [65536*9]                4,718,592   (base elem offset, dy|dx code)

__device__ __forceinline__ ushort_t f2bf(float f) {
    union { float f; unsigned int u; } v; v.f = f;
    unsigned int u = v.u;
    return (ushort_t)((u + 0x7fffu + ((u >> 16) & 1u)) >> 16);
}

__device__ __forceinline__ ushort2 pk_bf16(float a, float b) {
    __hip_bfloat162 h = __float22bfloat162_rn(make_float2(a, b));
    return *(ushort2*)&h;
}

__device__ __forceinline__ float bflo(unsigned v) {
    union { unsigned u; float f; } c; c.u = v << 16; return c.f;
}
__device__ __forceinline__ float bfhi(unsigned v) {
    union { unsigned u; float f; } c; c.u = v & 0xffff0000u; return c.f;
}

// ---------------- K0: x -> bf16, weight repack ----------------
__global__ __launch_bounds__(256) void k0_prep(
    const float* __restrict__ x, const float* __restrict__ kern,
    const float* __restrict__ offw, const float* __restrict__ modw,
    ushort_t* __restrict__ xbf, ushort_t* __restrict__ wt2,
    ushort_t* __restrict__ wom2) {
    const int gid = blockIdx.x, t = threadIdx.x;
    if (gid < 8192) {                       // x convert
        const int idx = gid * 256 + t;
        float4 v = ((const float4*)x)[idx];
        ushort4 u;
        u.x = f2bf(v.x); u.y = f2bf(v.y); u.z = f2bf(v.z); u.w = f2bf(v.w);
        ((ushort4*)xbf)[idx] = u;
    } else if (gid < 9344) {                // wt2: 294912 elems
        const int tid = (gid - 8192) * 256 + t;
        const int kpart = tid & 31, n = (tid >> 5) & 255, kcg = tid >> 13;
        const int k = kcg * 32 + kpart;     // k = tap*128 + c
        wt2[tid] = f2bf(kern[k * 256 + n]);
    } else {                                // wom2: 36864 elems
        const int tid = (gid - 9344) * 256 + t;
        const int kpart = tid & 31, n = (tid >> 5) & 31, kcg = tid >> 10;
        const int k = kcg * 32 + kpart;
        float v = 0.f;
        if (n < 18) v = offw[k * 18 + n];
        else if (n < 27) v = modw[k * 9 + (n - 18)];
        wom2[tid] = f2bf(v);
    }
}

// ---------------- K1: offset/mod conv + bilinear metadata ----------------
#define XSS 72   // padded channel stride (shorts)
__global__ __launch_bounds__(256) void k1_offsets(
    const ushort_t* __restrict__ xbf, const ushort_t* __restrict__ wom2,
    const float* __restrict__ offb, const float* __restrict__ modb,
    float4* __restrict__ metaw, int2* __restrict__ metai) {
    __shared__ ushort_t xs[3 * 130 * XSS];
    float* Cs = (float*)xs;
    const int bid = blockIdx.x;
    const int b = bid >> 7, h = bid & 127;
    const int t = threadIdx.x;
    const int lane = t & 63, wv = t >> 6;    // 4 waves
    const int ln = lane & 15, quad = lane >> 4;

    f32x4 acc[2][2];
#pragma unroll
    for (int i = 0; i < 2; ++i)
#pragma unroll
        for (int j = 0; j < 2; ++j) acc[i][j] = (f32x4){0.f, 0.f, 0.f, 0.f};

    for (int half = 0; half < 2; ++half) {
        for (int u = t; u < 768; u += 256) {
            const int r = u >> 8, rem = u & 255;
            const int xw = rem >> 1, sub = rem & 1;
            const int y = h + r - 1;
            ushort_t* dst = &xs[(r * 130 + xw + 1) * XSS + sub * 32];
            if ((unsigned)y < 128u) {
                const ushort_t* src = xbf + (((b * 128 + y) * 128 + xw) * 128) + half * 64 + sub * 32;
#pragma unroll
                for (int j = 0; j < 4; ++j)
                    *(int4*)(dst + j * 8) = *(const int4*)(src + j * 8);
            } else {
                const int4 z = make_int4(0, 0, 0, 0);
#pragma unroll
                for (int j = 0; j < 4; ++j) *(int4*)(dst + j * 8) = z;
            }
        }
        if (t < 48) {
            const int r = t >> 4, side = (t >> 3) & 1, j = t & 7;
            *(int4*)&xs[(r * 130 + side * 129) * XSS + j * 8] = make_int4(0, 0, 0, 0);
        }
        __syncthreads();
#pragma unroll
        for (int tap = 0; tap < 9; ++tap) {
            const int ky = tap / 3, kx = tap % 3;
#pragma unroll
            for (int kc = 0; kc < 2; ++kc) {
                const int col = kc * 32 + quad * 8;
                const ushort_t* arow = &xs[(ky * 130 + kx) * XSS + col];
                bf16x8 a0 = *(const bf16x8*)(arow + (wv * 32 + ln) * XSS);
                bf16x8 a1 = *(const bf16x8*)(arow + (wv * 32 + 16 + ln) * XSS);
                const int kcg = tap * 4 + half * 2 + kc;
                const ushort_t* bp = wom2 + kcg * 1024 + quad * 8;
                bf16x8 b0 = *(const bf16x8*)(bp + ln * 32);
                bf16x8 b1 = *(const bf16x8*)(bp + (ln + 16) * 32);
                acc[0][0] = __builtin_amdgcn_mfma_f32_16x16x32_bf16(a0, b0, acc[0][0], 0, 0, 0);
                acc[0][1] = __builtin_amdgcn_mfma_f32_16x16x32_bf16(a0, b1, acc[0][1], 0, 0, 0);
                acc[1][0] = __builtin_amdgcn_mfma_f32_16x16x32_bf16(a1, b0, acc[1][0], 0, 0, 0);
                acc[1][1] = __builtin_amdgcn_mfma_f32_16x16x32_bf16(a1, b1, acc[1][1], 0, 0, 0);
            }
        }
        __syncthreads();
    }
#pragma unroll
    for (int mi = 0; mi < 2; ++mi)
#pragma unroll
        for (int nt = 0; nt < 2; ++nt)
#pragma unroll
            for (int r = 0; r < 4; ++r) {
                const int m = wv * 32 + mi * 16 + quad * 4 + r;
                const int n = nt * 16 + ln;
                if (n < 27) Cs[m * 32 + n] = acc[mi][nt][r];
            }
    __syncthreads();
    const int px = t >> 1;
    const int p = bid * 128 + px;
    for (int tap = (t & 1); tap < 9; tap += 2) {
        const float oy = Cs[px * 32 + 2 * tap] + offb[2 * tap];
        const float ox = Cs[px * 32 + 2 * tap + 1] + offb[2 * tap + 1];
        float md = Cs[px * 32 + 18 + tap] + modb[tap];
        md = 1.f / (1.f + __expf(-md));
        const float gy = fminf(fmaxf((float)(tap / 3 - 1) + oy, 0.f), 127.f);
        const float gx = fminf(fmaxf((float)(tap % 3 - 1) + ox, 0.f), 127.f);
        const float y0f = floorf(gy), x0f = floorf(gx);
        const int y0 = (int)y0f, x0 = (int)x0f;
        const int dy = (y0 < 127) ? 16384 : 0;
        const int dx = (x0 < 127) ? 128 : 0;
        const float wy1 = gy - y0f, wx1 = gx - x0f;
        const float wy0 = 1.f - wy1, wx0 = 1.f - wx1;
        metaw[p * 9 + tap] = make_float4(md * wy0 * wx0, md * wy0 * wx1,
                                         md * wy1 * wx0, md * wy1 * wx1);
        metai[p * 9 + tap] = make_int2((y0 * 128 + x0) * 128, dy + dx);
    }
}

// ---------------- K2: fused sample + modulate + GEMM ----------------
// 1024 blocks (64 px each), 512 thr / 8 waves. Wave tile 64m x 32n (no B
// redundancy). bf16 gathers. Double-buffered XOR-swizzled LDS A tile.
__device__ __forceinline__ u16x8 lerp8(uint4 a, uint4 b, uint4 c, uint4 d, float4 w) {
    const unsigned* pa = (const unsigned*)&a;
    const unsigned* pb = (const unsigned*)&b;
    const unsigned* pc = (const unsigned*)&c;
    const unsigned* pd = (const unsigned*)&d;
    u16x8 r;
#pragma unroll
    for (int j = 0; j < 4; ++j) {
        float sl = w.x * bflo(pa[j]) + w.y * bflo(pb[j]) + w.z * bflo(pc[j]) + w.w * bflo(pd[j]);
        float sh = w.x * bfhi(pa[j]) + w.y * bfhi(pb[j]) + w.z * bfhi(pc[j]) + w.w * bfhi(pd[j]);
        ushort2 pk2 = pk_bf16(sl, sh);
        r[2 * j] = pk2.x; r[2 * j + 1] = pk2.y;
    }
    return r;
}

__device__ __forceinline__ void stage64(ushort_t* __restrict__ dst,
                                        const ushort_t* __restrict__ xb,
                                        int si, int cb, float4 w, int2 mi_) {
    const ushort_t* r00 = xb + mi_.x + cb * 16;
    const ushort_t* r01 = r00 + (mi_.y & 128);
    const ushort_t* r10 = r00 + (mi_.y & 16384);
    const ushort_t* r11 = r00 + mi_.y;
    uint4 u00a = *(const uint4*)r00, u00b = *(const uint4*)(r00 + 8);
    uint4 u01a = *(const uint4*)r01, u01b = *(const uint4*)(r01 + 8);
    uint4 u10a = *(const uint4*)r10, u10b = *(const uint4*)(r10 + 8);
    uint4 u11a = *(const uint4*)r11, u11b = *(const uint4*)(r11 + 8);
    const int sw = si & 15;
    *(u16x8*)&dst[si * 128 + (((cb * 2) ^ sw) << 3)]     = lerp8(u00a, u01a, u10a, u11a, w);
    *(u16x8*)&dst[si * 128 + (((cb * 2 + 1) ^ sw) << 3)] = lerp8(u00b, u01b, u10b, u11b, w);
}

__global__ __launch_bounds__(512, 4) void k2_main(
    const ushort_t* __restrict__ xbf, const ushort_t* __restrict__ wt2,
    const float4* __restrict__ metaw, const int2* __restrict__ metai,
    const float* __restrict__ bias, float* __restrict__ out) {
    __shared__ ushort_t As[2 * 8192];   // 32 KB: two 64x128 bf16 tiles, XOR-swizzled
    const int bid = blockIdx.x;
    const int b = bid >> 8;
    const int t = threadIdx.x;
    const int lane = t & 63, wv = t >> 6;      // 8 waves
    const int ln = lane & 15, quad = lane >> 4;
    const int ng = wv;                         // n-slice base = ng*32
    const int p0 = bid * 64;

    f32x4 acc[4][2];
#pragma unroll
    for (int i = 0; i < 4; ++i)
#pragma unroll
        for (int j = 0; j < 2; ++j) acc[i][j] = (f32x4){0.f, 0.f, 0.f, 0.f};

    const int si = t >> 3, cb = t & 7;         // 64 px x 8 ch-groups (16 ch)
    const int p = p0 + si;
    const ushort_t* xb = xbf + b * (1 << 21);

    float4 mw0 = metaw[p * 9];
    int2 mi0 = metai[p * 9];
    stage64(As, xb, si, cb, mw0, mi0);
    float4 mwN = metaw[p * 9 + 1];
    int2 miN = metai[p * 9 + 1];
    __syncthreads();

    for (int tap = 0; tap < 9; ++tap) {
        const ushort_t* buf = As + (tap & 1) * 8192;
#pragma unroll
        for (int kc = 0; kc < 4; ++kc) {
            const int chunk = kc * 4 + quad;
            bf16x8 a[4], bb[2];
#pragma unroll
            for (int mi2 = 0; mi2 < 4; ++mi2) {
                const int m = mi2 * 16 + ln;
                a[mi2] = *(const bf16x8*)&buf[m * 128 + ((chunk ^ ln) << 3)];
            }
            const int kcg = tap * 4 + kc;
#pragma unroll
            for (int nj = 0; nj < 2; ++nj) {
                const int n = ng * 32 + nj * 16 + ln;
                bb[nj] = *(const bf16x8*)&wt2[(kcg * 256 + n) * 32 + quad * 8];
            }
#pragma unroll
            for (int mi2 = 0; mi2 < 4; ++mi2)
#pragma unroll
                for (int nj = 0; nj < 2; ++nj)
                    acc[mi2][nj] = __builtin_amdgcn_mfma_f32_16x16x32_bf16(
                        a[mi2], bb[nj], acc[mi2][nj], 0, 0, 0);
        }
        if (tap < 8) {
            float4 mwP; int2 miP;
            if (tap < 7) { mwP = metaw[p * 9 + tap + 2]; miP = metai[p * 9 + tap + 2]; }
            stage64(As + ((tap + 1) & 1) * 8192, xb, si, cb, mwN, miN);
            mwN = mwP; miN = miP;
        }
        __syncthreads();
    }
#pragma unroll
    for (int mi2 = 0; mi2 < 4; ++mi2)
#pragma unroll
        for (int nj = 0; nj < 2; ++nj) {
            const int n = ng * 32 + nj * 16 + ln;
            const float bs = bias[n];
#pragma unroll
            for (int r = 0; r < 4; ++r) {
                const int m = mi2 * 16 + quad * 4 + r;
                out[(p0 + m) * 256 + n] = acc[mi2][nj][r] + bs;
            }
        }
}

extern "C" void kernel_launch(void* const* d_in, const int* in_sizes, int n_in,
                              void* d_out, int out_size, void* d_ws, size_t ws_size,
                              hipStream_t stream) {
    const float* x    = (const float*)d_in[0];
    const float* offw = (const float*)d_in[1];
    const float* offb = (const float*)d_in[2];
    const float* modw = (const float*)d_in[3];
    const float* modb = (const float*)d_in[4];
    const float* kern = (const float*)d_in[5];
    const float* bias = (const float*)d_in[6];
    float* out = (float*)d_out;

    char* ws = (char*)d_ws;
    ushort_t* xbf   = (ushort_t*)(ws);
    ushort_t* wt2   = (ushort_t*)(ws + 16777216);
    ushort_t* wom2  = (ushort_t*)(ws + 17367040);
    float4*   metaw = (float4*)(ws + 17440768);
    int2*     metai = (int2*)(ws + 26877952);

    k0_prep<<<9488, 256, 0, stream>>>(x, kern, offw, modw, xbf, wt2, wom2);
    k1_offsets<<<512, 256, 0, stream>>>(xbf, wom2, offb, modb, metaw, metai);
    k2_main<<<1024, 512, 0, stream>>>(xbf, wt2, metaw, metai, bias, out);
}